// Round 13
// baseline (179.099 us; speedup 1.0000x reference)
//
#include <hip/hip_runtime.h>

#define N_NODES 100000
#define N_EDGES 1600000
#define D 64
#define CAP 32         // slot cap per node; Poisson(16): P(deg>32)~1e-5/node
#define OVF_CAP 4096   // global overflow list (backstop)
#define LOVF_CAP 256   // per-block LDS overflow list (R20)
#define N_TILES 1563   // (N_NODES + 63) / 64
#define NR 8           // (legacy fill) region groups
#define SLICE_EDGES 2048
#define N_SLICES 782   // ceil(N_EDGES / SLICE_EDGES)
#define R1_BLOCKS 64   // stage-1 reduce blocks (legacy tiers)
#define ASTRIDE 136    // final LDS row stride in bf16 elems (128 + 8 pad)

// Bucketed partition (R21 scan-free) + fused LDS-CSR gather (R17/R20)
#define NB2 782        // buckets of 128 nodes (dst>>7)
#define BCAP2 2560     // per-bucket capacity (mean 2048, sigma~45 -> +11 sigma)
#define EPB 4096       // edges per partition block
#define P1_BLOCKS 391  // ceil(N_EDGES / EPB)
#define CVT_BLOCKS 256 // rider blocks: emb->fp8 (+ rid0 zeroes out)

// Persistent-tile final (R18)
#define F2_TPB 3       // tiles per block
#define F2_BLOCKS 521  // 521 * 3 == 1563 exactly

typedef int    vint4  __attribute__((ext_vector_type(4)));
typedef short  s16x4  __attribute__((ext_vector_type(4)));
typedef short  s16x8  __attribute__((ext_vector_type(8)));
typedef float  f32x2  __attribute__((ext_vector_type(2)));
typedef float  f32x4  __attribute__((ext_vector_type(4)));
typedef __bf16 bf16x8 __attribute__((ext_vector_type(8)));  // MFMA operand type

// f32 -> bf16 (RNE). Inputs are finite; NaN path not needed.
__device__ inline short f2bf(float f) {
    unsigned u = __builtin_bit_cast(unsigned, f);
    u += 0x7fffu + ((u >> 16) & 1u);
    return (short)(u >> 16);
}
__device__ inline s16x4 f2bf4(float4 v) {
    s16x4 r; r.x = f2bf(v.x); r.y = f2bf(v.y); r.z = f2bf(v.z); r.w = f2bf(v.w);
    return r;
}
__device__ inline float bf2f(short s) {
    return __builtin_bit_cast(float, ((unsigned)(unsigned short)s) << 16);
}

// ws layout (bytes), top tier:
//   bkt    @ 0        : NB2*BCAP2 int         (8.0 MB)
//   acc16  @ 13201408 : N_NODES*D bf16        (12.8 MB)
//   ovfc   @ 38801408 : int                              } one memset covers
//   bcnt   @ 38801424 : NB2 int (3128 B)                 } ovfc+bcnt
//   ovf    @ 38804560 : OVF_CAP int2          (32 KB)
//   part   @ 38867200 : reduce scratch (legacy tiers)
//   part2  @ 39267328 : R1_BLOCKS*64 float    (16 KB)
//   emb8   @ 39283712 : N_NODES*D bytes       (6.4 MB, OCP e4m3)
#define WS_SLOTS_OFF  401408     // mid-tier CSR slots
#define WS_ACC_OFF    13201408   // mid-tier f32 acc (25.6 MB)
#define WS_ACC16_OFF  13201408
#define WS_OVFC_OFF   38801408
#define WS_BCNT_OFF   38801424
#define WS_OVF_OFF    38804560
#define WS_PART_OFF   38867200
#define WS_PART2_OFF  39267328
#define WS_EMB8_OFF   39283712
#define WS_NEEDED     (WS_PART2_OFF + R1_BLOCKS * 64 * 4)
#define WS_NEEDED16   (WS_EMB8_OFF + N_NODES * D * 2)

// ---------------------------------------------------------------------------
// R21 pass 1: SCAN-FREE edge partition. The R12-lineage Hillis-Steele scan
// (20 barriers, 28KB staging LDS) only bought coalesced copy-out; L2 write-
// combining on ~5-edge bucket runs makes that unnecessary. New flow:
// LDS hist (proven) -> one global reserve atomicAdd per (block,bucket)
// (R19-proven volume: 306K total, ~391/address, parallel across addrs) ->
// per-edge LDS-cursor atomic + direct 4B store into the bucket's global
// region. LDS 35KB -> 6.2KB; per-edge instruction count roughly halved.
// fillgather is order-insensitive within a bucket -> permutation is fine.
// Rider blocks: emb -> OCP e4m3 via HW cvt_pk_fp8; rid 0 zeroes out.
// ---------------------------------------------------------------------------
__global__ __launch_bounds__(512) void part_kernel(
    const int* __restrict__ edge_src, const int* __restrict__ edge_dst,
    int* __restrict__ bcnt, int* __restrict__ bkt,
    int* __restrict__ ovf_cnt, int2* __restrict__ ovf,
    const float* __restrict__ emb, unsigned* __restrict__ emb8,
    float* __restrict__ out) {
    const int tid = threadIdx.x;
    if (blockIdx.x >= P1_BLOCKS) {
        const int rid = blockIdx.x - P1_BLOCKS;
        if (rid == 0 && tid < 64) out[tid] = 0.f;
        const float4* e4 = (const float4*)emb;
        const unsigned t0 = rid * 512 + tid;
        for (unsigned j = t0; j < (unsigned)(N_NODES * D / 4);
             j += CVT_BLOCKS * 512) {
            float4 v = e4[j];
            int w = 0;
            w = __builtin_amdgcn_cvt_pk_fp8_f32(v.x, v.y, w, false);
            w = __builtin_amdgcn_cvt_pk_fp8_f32(v.z, v.w, w, true);
            emb8[j] = (unsigned)w;
        }
        return;
    }

    __shared__ int hist[NB2];   // 3.1 KB
    __shared__ int curb[NB2];   // 3.1 KB: global write cursor per bucket

    const int e0 = blockIdx.x * EPB;
    for (int i = tid; i < NB2; i += 512) hist[i] = 0;
    __syncthreads();

    int ss[8], dd[8];
#pragma unroll
    for (int i = 0; i < 8; ++i) {
        const int e = e0 + i * 512 + tid;
        if (e < N_EDGES) { ss[i] = edge_src[e]; dd[i] = edge_dst[e]; }
        else             { ss[i] = 0; dd[i] = -1; }
    }

#pragma unroll
    for (int i = 0; i < 8; ++i)
        if (dd[i] >= 0) atomicAdd(&hist[dd[i] >> 7], 1);
    __syncthreads();

    // Reserve this block's slice of each bucket (one global atomic each).
    for (int i = tid; i < NB2; i += 512) {
        const int h = hist[i];
        curb[i] = (h > 0) ? atomicAdd(&bcnt[i], h) : 0;
    }
    __syncthreads();

    // Direct scatter: LDS cursor gives the global position.
#pragma unroll
    for (int i = 0; i < 8; ++i) {
        if (dd[i] >= 0) {
            const int b = dd[i] >> 7;
            const int gpos = atomicAdd(&curb[b], 1);
            const int pk = (ss[i] << 7) | (dd[i] & 127);
            if (gpos < BCAP2) {
                bkt[b * BCAP2 + gpos] = pk;
            } else {
                int oj = atomicAdd(ovf_cnt, 1);
                if (oj < OVF_CAP) ovf[oj] = make_int2(ss[i], dd[i]);
            }
        }
    }
}

// ---------------------------------------------------------------------------
// R20 fused fill+gather+overflow: block = one 128-node bucket, CSR in LDS.
// Phase 1: int atomicAdd directly on __shared__ (ds fast path); node-CAP
// overflow -> per-block LDS side list (global ovf as last backstop).
// Phase 2: register-sum gather, 16 nodes/wave, runtime-deg loop, HW fp8
// decode, bf16 store at the producer. Post-pass (wave 0, serial, same-block
// so no cross-block race): apply LDS side list + any global-ovf entries for
// this bucket via bf16 RMW.
// ---------------------------------------------------------------------------
__global__ __launch_bounds__(512) void fillgather_kernel(
    const int* __restrict__ bcnt, const int* __restrict__ bkt,
    const unsigned* __restrict__ emb8,
    int* __restrict__ ovf_cnt, int2* __restrict__ ovf,
    short* __restrict__ acc16) {
    __shared__ int lcnt[128];
    __shared__ int lslots[128 * CAP];   // 16 KB
    __shared__ int lovf[LOVF_CAP];      // 1 KB: packed (src<<7)|dl
    __shared__ int lovf_cnt;
    const int b = blockIdx.x;
    const int tid = threadIdx.x;
    if (tid < 128) lcnt[tid] = 0;
    if (tid == 0) lovf_cnt = 0;
    __syncthreads();

    int n = bcnt[b];
    if (n > BCAP2) n = BCAP2;
    for (int i = tid; i < n; i += 512) {
        const int pk = bkt[b * BCAP2 + i];
        const int dl = pk & 127;
        const int pos = atomicAdd(&lcnt[dl], 1);    // int LDS atomic (fast)
        if (pos < CAP) {
            lslots[dl * CAP + pos] = pk >> 7;
        } else {
            int j = atomicAdd(&lovf_cnt, 1);
            if (j < LOVF_CAP) {
                lovf[j] = pk;
            } else {
                int g = atomicAdd(ovf_cnt, 1);      // ultimate backstop
                if (g < OVF_CAP) ovf[g] = make_int2(pk >> 7, (b << 7) | dl);
            }
        }
    }
    __syncthreads();

    const int lane = tid & 63;
    const int wave = tid >> 6;
    const int q = lane >> 4;
    const int c = lane & 15;
#pragma unroll 1
    for (int t = 0; t < 16; ++t) {
        const int dl = wave * 16 + t;
        const int v = (b << 7) | dl;
        int deg = lcnt[dl];
        if (deg > CAP) deg = CAP;
        const int si = lslots[dl * CAP + (lane & (CAP - 1))];

        float4 sum = make_float4(0.f, 0.f, 0.f, 0.f);
        for (int e = 0; e < deg; e += 8) {
            const int i0 = e + q, i1 = e + 4 + q;
            const int s0 = __shfl(si, i0 & (CAP - 1));
            const int s1 = __shfl(si, i1 & (CAP - 1));
            unsigned x0 = 0u, x1 = 0u;
            if (i0 < deg) x0 = emb8[(unsigned)s0 * 16 + c];
            if (i1 < deg) x1 = emb8[(unsigned)s1 * 16 + c];
            const f32x2 a0 = __builtin_amdgcn_cvt_pk_f32_fp8((int)x0, false);
            const f32x2 a1 = __builtin_amdgcn_cvt_pk_f32_fp8((int)x0, true);
            const f32x2 b0 = __builtin_amdgcn_cvt_pk_f32_fp8((int)x1, false);
            const f32x2 b1 = __builtin_amdgcn_cvt_pk_f32_fp8((int)x1, true);
            sum.x += a0.x + b0.x;
            sum.y += a0.y + b0.y;
            sum.z += a1.x + b1.x;
            sum.w += a1.y + b1.y;
        }
#pragma unroll
        for (int off = 16; off < 64; off <<= 1) {
            sum.x += __shfl_xor(sum.x, off);
            sum.y += __shfl_xor(sum.y, off);
            sum.z += __shfl_xor(sum.z, off);
            sum.w += __shfl_xor(sum.w, off);
        }
        if (q == 0 && v < N_NODES) {
            *(s16x4*)&acc16[v * D + c * 4] = f2bf4(sum);
        }
    }
    __syncthreads();

    // Post-pass: overflow RMW (typically 0 entries). Wave 0 only; serial
    // over entries (same block -> ordered); 16 lanes x 4 dims per entry.
    if (wave == 0) {
        int nl = lovf_cnt;
        if (nl > LOVF_CAP) nl = LOVF_CAP;
        for (int i = 0; i < nl; ++i) {
            const int pk = lovf[i];
            const int v = (b << 7) | (pk & 127);
            if (lane < 16) {
                const unsigned x = emb8[(unsigned)(pk >> 7) * 16 + lane];
                const f32x2 lo = __builtin_amdgcn_cvt_pk_f32_fp8((int)x, false);
                const f32x2 hi = __builtin_amdgcn_cvt_pk_f32_fp8((int)x, true);
                s16x4 cu = *(s16x4*)&acc16[v * D + lane * 4];
                s16x4 r;
                r.x = f2bf(bf2f(cu.x) + lo.x);
                r.y = f2bf(bf2f(cu.y) + lo.y);
                r.z = f2bf(bf2f(cu.z) + hi.x);
                r.w = f2bf(bf2f(cu.w) + hi.y);
                *(s16x4*)&acc16[v * D + lane * 4] = r;
            }
        }
        int ng = *ovf_cnt;
        if (ng > OVF_CAP) ng = OVF_CAP;
        for (int i = 0; i < ng; ++i) {
            const int2 e = ovf[i];
            if ((e.y >> 7) != b) continue;
            if (lane < 16) {
                const unsigned x = emb8[(unsigned)e.x * 16 + lane];
                const f32x2 lo = __builtin_amdgcn_cvt_pk_f32_fp8((int)x, false);
                const f32x2 hi = __builtin_amdgcn_cvt_pk_f32_fp8((int)x, true);
                s16x4 cu = *(s16x4*)&acc16[e.y * D + lane * 4];
                s16x4 r;
                r.x = f2bf(bf2f(cu.x) + lo.x);
                r.y = f2bf(bf2f(cu.y) + lo.y);
                r.z = f2bf(bf2f(cu.z) + hi.x);
                r.w = f2bf(bf2f(cu.w) + hi.y);
                *(s16x4*)&acc16[e.y * D + lane * 4] = r;
            }
        }
    }
}

// ---------------------------------------------------------------------------
// Legacy region fill + f32 gather + f32 ovf (mid tier / fallback only).
// ---------------------------------------------------------------------------
__global__ __launch_bounds__(256) void fill_kernel(
    const int* __restrict__ edge_src, const int* __restrict__ edge_dst,
    int* __restrict__ cnt, int* __restrict__ slots,
    int* __restrict__ ovf_cnt, int2* __restrict__ ovf) {
    const int r = blockIdx.x & (NR - 1);
    if (r == 7) return;
    const int slice = blockIdx.x >> 3;
    const int base_e = slice * SLICE_EDGES + threadIdx.x * 8;
    if (base_e >= N_EDGES) return;
    const vint4* s4 = (const vint4*)(edge_src + base_e);
    const vint4* d4 = (const vint4*)(edge_dst + base_e);
    vint4 a0 = __builtin_nontemporal_load(s4);
    vint4 a1 = __builtin_nontemporal_load(s4 + 1);
    vint4 b0 = __builtin_nontemporal_load(d4);
    vint4 b1 = __builtin_nontemporal_load(d4 + 1);
    int ss[8] = {a0.x, a0.y, a0.z, a0.w, a1.x, a1.y, a1.z, a1.w};
    int dd[8] = {b0.x, b0.y, b0.z, b0.w, b1.x, b1.y, b1.z, b1.w};
    int pos[8];
#pragma unroll
    for (int i = 0; i < 8; ++i) {
        pos[i] = ((dd[i] >> 14) == r) ? atomicAdd(&cnt[dd[i]], 1) : -1;
    }
#pragma unroll
    for (int i = 0; i < 8; ++i) {
        if (pos[i] >= 0 && pos[i] < CAP) slots[dd[i] * CAP + pos[i]] = ss[i];
    }
#pragma unroll
    for (int i = 0; i < 8; ++i) {
        if (pos[i] >= CAP) {
            int j = atomicAdd(ovf_cnt, 1);
            if (j < OVF_CAP) ovf[j] = make_int2(ss[i], dd[i]);
        }
    }
}

__global__ __launch_bounds__(256) void gather_kernel(
    const float* __restrict__ emb, const int* __restrict__ cnt,
    const int* __restrict__ slots, float* __restrict__ acc) {
    const int lane = threadIdx.x & 63;
    const int wave = threadIdx.x >> 6;
    const int v = blockIdx.x * 4 + wave;
    const int q  = lane >> 4;
    const int c4 = lane & 15;
    int deg = cnt[v];
    if (deg > CAP) deg = CAP;
    const int si = slots[v * CAP + (lane & (CAP - 1))];
    const float4* emb4 = (const float4*)emb;

    float4 sum = make_float4(0.f, 0.f, 0.f, 0.f);
    for (int e = 0; e < deg; e += 4) {
        const int idx = e + q;
        const int s = __shfl(si, idx & (CAP - 1));
        if (idx < deg) {
            float4 a = emb4[s * 16 + c4];
            sum.x += a.x; sum.y += a.y; sum.z += a.z; sum.w += a.w;
        }
    }
#pragma unroll
    for (int off = 16; off < 64; off <<= 1) {
        sum.x += __shfl_xor(sum.x, off);
        sum.y += __shfl_xor(sum.y, off);
        sum.z += __shfl_xor(sum.z, off);
        sum.w += __shfl_xor(sum.w, off);
    }
    if (q == 0) {
        ((float4*)acc)[v * 16 + c4] = sum;
    }
}

__global__ __launch_bounds__(256) void ovf_kernel(
    const float* __restrict__ emb, const int* __restrict__ ovf_cnt,
    const int2* __restrict__ ovf, float* __restrict__ acc) {
    int n = *ovf_cnt;
    if (n > OVF_CAP) n = OVF_CAP;
    const int lane = threadIdx.x & 63;
    const int wv = (blockIdx.x * 256 + threadIdx.x) >> 6;
    const int nwaves = (gridDim.x * 256) >> 6;
    for (int i = wv; i < n; i += nwaves) {
        int2 e = ovf[i];
        unsafeAtomicAdd(&acc[e.y * D + lane], emb[e.x * D + lane]);
    }
}

__global__ __launch_bounds__(256) void scatter_kernel(
    const float* __restrict__ emb,
    const int* __restrict__ edge_src, const int* __restrict__ edge_dst,
    float* __restrict__ acc) {
    int gid = blockIdx.x * 256 + threadIdx.x;
    int e = gid >> 6;
    int c = gid & 63;
    unsafeAtomicAdd(&acc[edge_dst[e] * D + c], emb[edge_src[e] * D + c]);
}

// ---------------------------------------------------------------------------
// R20 persistent-tile final: 521 blocks x 3 tiles; W staged + Bf hoisted once
// per block; per-thread sums across tiles; block result accumulated directly
// into out via unsafeAtomicAdd (out zeroed by part's rider).
// ---------------------------------------------------------------------------
__global__ __launch_bounds__(256) void final_mixed2_kernel(
    const float* __restrict__ feat, const short* __restrict__ acc16,
    const float* __restrict__ W1, const float* __restrict__ b1,
    const float* __restrict__ W2, const float* __restrict__ b2,
    float* __restrict__ out) {
    __shared__ short A_s[64 * ASTRIDE];
    __shared__ short W_s[64 * ASTRIDE];
    __shared__ float red[4][64];

    const int tid  = threadIdx.x;
    const int lane = tid & 63;
    const int wave = tid >> 6;
    const int quad = lane >> 4;
    const int col  = lane & 15;

    float bias[4];
#pragma unroll
    for (int nb = 0; nb < 4; ++nb) {
        const int o = nb * 16 + col;
        bias[nb] = b1[o] + b2[o];
    }

    // Stage W once (f32 -> bf16).
    {
        const float4* W1v = (const float4*)W1;
        const float4* W2v = (const float4*)W2;
#pragma unroll
        for (int i = 0; i < 4; ++i) {
            const int flat = tid + i * 256;   // 0..1023
            const int row = flat >> 4, c4 = flat & 15;
            *(s16x4*)&W_s[row * ASTRIDE + c4 * 4]      = f2bf4(W1v[flat]);
            *(s16x4*)&W_s[row * ASTRIDE + 64 + c4 * 4] = f2bf4(W2v[flat]);
        }
    }
    __syncthreads();

    // Hoist B-fragments once.
    bf16x8 Bf[4][4];
#pragma unroll
    for (int nb = 0; nb < 4; ++nb)
#pragma unroll
        for (int ks = 0; ks < 4; ++ks)
            Bf[nb][ks] = __builtin_bit_cast(bf16x8,
                *(const s16x8*)&W_s[(nb * 16 + col) * ASTRIDE + ks * 32 + quad * 8]);

    float sums[4] = {0.f, 0.f, 0.f, 0.f};

#pragma unroll 1
    for (int t = 0; t < F2_TPB; ++t) {
        const int tile = blockIdx.x * F2_TPB + t;   // 521*3 == 1563: no guard
        const int node0 = tile * 64;

        // Stage A: feat half (f32->bf16) + nbr half (bf16 copy).
        {
            const float4* fv = (const float4*)feat;
#pragma unroll
            for (int i = 0; i < 4; ++i) {
                const int flat = tid + i * 256;
                const int row = flat >> 4, c4 = flat & 15;
                const int node = node0 + row;
                float4 f = make_float4(0.f, 0.f, 0.f, 0.f);
                if (node < N_NODES) f = fv[(size_t)node * 16 + c4];
                *(s16x4*)&A_s[row * ASTRIDE + c4 * 4] = f2bf4(f);
            }
#pragma unroll
            for (int i = 0; i < 2; ++i) {
                const int flat = tid + i * 256;   // 0..511
                const int row = flat >> 3, c = flat & 7;
                const int node = node0 + row;
                s16x8 pk = {0, 0, 0, 0, 0, 0, 0, 0};
                if (node < N_NODES) pk = *(const s16x8*)&acc16[node * D + c * 8];
                *(s16x8*)&A_s[row * ASTRIDE + 64 + c * 8] = pk;
            }
        }
        __syncthreads();

        f32x4 C[4];
#pragma unroll
        for (int nb = 0; nb < 4; ++nb) C[nb] = (f32x4){0.f, 0.f, 0.f, 0.f};
#pragma unroll
        for (int ks = 0; ks < 4; ++ks) {
            const bf16x8 Af = __builtin_bit_cast(bf16x8,
                *(const s16x8*)&A_s[(wave * 16 + col) * ASTRIDE + ks * 32 + quad * 8]);
#pragma unroll
            for (int nb = 0; nb < 4; ++nb)
                C[nb] = __builtin_amdgcn_mfma_f32_16x16x32_bf16(Af, Bf[nb][ks],
                                                                C[nb], 0, 0, 0);
        }

        // Epilogue: bias + ReLU, masked accumulate into per-thread sums.
#pragma unroll
        for (int nb = 0; nb < 4; ++nb) {
#pragma unroll
            for (int reg = 0; reg < 4; ++reg) {
                const int node = node0 + wave * 16 + quad * 4 + reg;
                float u = C[nb][reg] + bias[nb];
                u = (u > 0.f) ? u : 0.f;
                if (node < N_NODES) sums[nb] += u;
            }
        }
        __syncthreads();   // all waves done reading A_s before next overwrite
    }

    // One cross-lane + cross-wave reduction, then atomic into out.
#pragma unroll
    for (int nb = 0; nb < 4; ++nb) {
        sums[nb] += __shfl_xor(sums[nb], 16);
        sums[nb] += __shfl_xor(sums[nb], 32);
        if (lane < 16) red[wave][nb * 16 + lane] = sums[nb];
    }
    __syncthreads();
    if (tid < 64) {
        unsafeAtomicAdd(&out[tid],
            red[0][tid] + red[1][tid] + red[2][tid] + red[3][tid]);
    }
}

// ---------------------------------------------------------------------------
// Legacy f32-input final (mid tier / fallback): one tile per block.
// ---------------------------------------------------------------------------
__global__ __launch_bounds__(256) void final_kernel(
    const float* __restrict__ feat, const float* __restrict__ acc,
    const float* __restrict__ W1, const float* __restrict__ b1,
    const float* __restrict__ W2, const float* __restrict__ b2,
    float* __restrict__ partials) {
    __shared__ short A_s[64 * ASTRIDE];
    __shared__ short W_s[64 * ASTRIDE];
    __shared__ float red[4][64];

    const int tid  = threadIdx.x;
    const int lane = tid & 63;
    const int wave = tid >> 6;
    const int quad = lane >> 4;
    const int col  = lane & 15;
    const int node0 = blockIdx.x * 64;

    float bias[4];
#pragma unroll
    for (int nb = 0; nb < 4; ++nb) {
        const int o = nb * 16 + col;
        bias[nb] = b1[o] + b2[o];
    }

    {
        const float4* W1v = (const float4*)W1;
        const float4* W2v = (const float4*)W2;
#pragma unroll
        for (int i = 0; i < 4; ++i) {
            const int flat = tid + i * 256;
            const int row = flat >> 4, c4 = flat & 15;
            *(s16x4*)&W_s[row * ASTRIDE + c4 * 4]      = f2bf4(W1v[flat]);
            *(s16x4*)&W_s[row * ASTRIDE + 64 + c4 * 4] = f2bf4(W2v[flat]);
        }
    }

    {
        const float4* fv = (const float4*)feat;
        const float4* av = (const float4*)acc;
#pragma unroll
        for (int i = 0; i < 4; ++i) {
            const int flat = tid + i * 256;
            const int row = flat >> 4, c4 = flat & 15;
            const int node = node0 + row;
            float4 f = make_float4(0.f, 0.f, 0.f, 0.f);
            float4 n = make_float4(0.f, 0.f, 0.f, 0.f);
            if (node < N_NODES) {
                f = fv[(size_t)node * 16 + c4];
                n = av[(size_t)node * 16 + c4];
            }
            *(s16x4*)&A_s[row * ASTRIDE + c4 * 4]      = f2bf4(f);
            *(s16x4*)&A_s[row * ASTRIDE + 64 + c4 * 4] = f2bf4(n);
        }
    }
    __syncthreads();

    bf16x8 Bf[4][4];
#pragma unroll
    for (int nb = 0; nb < 4; ++nb)
#pragma unroll
        for (int ks = 0; ks < 4; ++ks)
            Bf[nb][ks] = __builtin_bit_cast(bf16x8,
                *(const s16x8*)&W_s[(nb * 16 + col) * ASTRIDE + ks * 32 + quad * 8]);

    f32x4 C[4];
#pragma unroll
    for (int nb = 0; nb < 4; ++nb) C[nb] = (f32x4){0.f, 0.f, 0.f, 0.f};
#pragma unroll
    for (int ks = 0; ks < 4; ++ks) {
        const bf16x8 Af = __builtin_bit_cast(bf16x8,
            *(const s16x8*)&A_s[(wave * 16 + col) * ASTRIDE + ks * 32 + quad * 8]);
#pragma unroll
        for (int nb = 0; nb < 4; ++nb)
            C[nb] = __builtin_amdgcn_mfma_f32_16x16x32_bf16(Af, Bf[nb][ks],
                                                            C[nb], 0, 0, 0);
    }

    float sums[4] = {0.f, 0.f, 0.f, 0.f};
#pragma unroll
    for (int nb = 0; nb < 4; ++nb) {
#pragma unroll
        for (int reg = 0; reg < 4; ++reg) {
            const int node = node0 + wave * 16 + quad * 4 + reg;
            float u = C[nb][reg] + bias[nb];
            u = (u > 0.f) ? u : 0.f;
            if (node < N_NODES) sums[nb] += u;
        }
        sums[nb] += __shfl_xor(sums[nb], 16);
        sums[nb] += __shfl_xor(sums[nb], 32);
        if (lane < 16) red[wave][nb * 16 + lane] = sums[nb];
    }
    __syncthreads();
    if (tid < 64) {
        partials[blockIdx.x * 64 + tid] =
            red[0][tid] + red[1][tid] + red[2][tid] + red[3][tid];
    }
}

// ---------------------------------------------------------------------------
// Two-stage partials reduction (legacy tiers only).
// ---------------------------------------------------------------------------
__global__ __launch_bounds__(256) void reduce1_kernel(
    const float* __restrict__ partials, float* __restrict__ part2,
    int nrows, int rpb) {
    __shared__ float red[4][64];
    const int col = threadIdx.x & 63;
    const int seg = threadIdx.x >> 6;
    const int r0 = blockIdx.x * rpb;
    int r1 = r0 + rpb;
    if (r1 > nrows) r1 = nrows;
    float s = 0.f;
    for (int r = r0 + seg; r < r1; r += 4) s += partials[r * 64 + col];
    red[seg][col] = s;
    __syncthreads();
    if (seg == 0) {
        part2[blockIdx.x * 64 + col] =
            red[0][col] + red[1][col] + red[2][col] + red[3][col];
    }
}

__global__ __launch_bounds__(256) void reduce2_kernel(
    const float* __restrict__ part2, float* __restrict__ out) {
    __shared__ float red[4][64];
    const int col = threadIdx.x & 63;
    const int seg = threadIdx.x >> 6;
    float s = 0.f;
    for (int r = seg; r < R1_BLOCKS; r += 4) s += part2[r * 64 + col];
    red[seg][col] = s;
    __syncthreads();
    if (seg == 0) {
        out[col] = red[0][col] + red[1][col] + red[2][col] + red[3][col];
    }
}

extern "C" void kernel_launch(void* const* d_in, const int* in_sizes, int n_in,
                              void* d_out, int out_size, void* d_ws, size_t ws_size,
                              hipStream_t stream) {
    const float* feat = (const float*)d_in[0];
    const float* emb  = (const float*)d_in[1];
    const float* W1   = (const float*)d_in[2];
    const float* b1   = (const float*)d_in[3];
    const float* W2   = (const float*)d_in[4];
    const float* b2   = (const float*)d_in[5];
    const int* edge_src = (const int*)d_in[6];
    const int* edge_dst = (const int*)d_in[7];
    float* out = (float*)d_out;
    char* ws = (char*)d_ws;

    if (ws_size >= (size_t)WS_NEEDED16) {
        // R21 path: 4 dispatches (memset, part, fillgather, final).
        int*      bkt      = (int*)ws;
        short*    acc16    = (short*)(ws + WS_ACC16_OFF);
        int*      ovf_cnt  = (int*)(ws + WS_OVFC_OFF);
        int*      bcnt     = (int*)(ws + WS_BCNT_OFF);
        int2*     ovf      = (int2*)(ws + WS_OVF_OFF);
        unsigned* emb8     = (unsigned*)(ws + WS_EMB8_OFF);

        (void)hipMemsetAsync(ovf_cnt, 0, 16 + NB2 * sizeof(int), stream);

        part_kernel<<<P1_BLOCKS + CVT_BLOCKS, 512, 0, stream>>>(
            edge_src, edge_dst, bcnt, bkt, ovf_cnt, ovf, emb, emb8, out);
        fillgather_kernel<<<NB2, 512, 0, stream>>>(bcnt, bkt, emb8,
                                                   ovf_cnt, ovf, acc16);
        final_mixed2_kernel<<<F2_BLOCKS, 256, 0, stream>>>(feat, acc16, W1, b1,
                                                           W2, b2, out);
    } else if (ws_size >= (size_t)WS_NEEDED) {
        int*   cnt      = (int*)ws;
        int*   slots    = (int*)(ws + WS_SLOTS_OFF);
        float* acc      = (float*)(ws + WS_ACC_OFF);
        int*   ovf_cnt  = (int*)(ws + WS_OVFC_OFF);
        int2*  ovf      = (int2*)(ws + WS_OVF_OFF);
        float* partials = (float*)(ws + WS_PART_OFF);
        float* part2    = (float*)(ws + WS_PART2_OFF);

        (void)hipMemsetAsync(cnt, 0, N_NODES * sizeof(int), stream);
        (void)hipMemsetAsync(ovf_cnt, 0, sizeof(int), stream);

        fill_kernel<<<NR * N_SLICES, 256, 0, stream>>>(edge_src, edge_dst,
                                                       cnt, slots, ovf_cnt, ovf);
        gather_kernel<<<N_NODES / 4, 256, 0, stream>>>(emb, cnt, slots, acc);
        ovf_kernel<<<16, 256, 0, stream>>>(emb, ovf_cnt, ovf, acc);

        final_kernel<<<N_TILES, 256, 0, stream>>>(feat, acc, W1, b1, W2, b2,
                                                  partials);
        reduce1_kernel<<<R1_BLOCKS, 256, 0, stream>>>(partials, part2,
                                                      N_TILES, 25);
        reduce2_kernel<<<1, 256, 0, stream>>>(part2, out);
    } else {
        float* acc = (float*)ws;
        (void)hipMemsetAsync(acc, 0, (size_t)N_NODES * D * sizeof(float), stream);
        scatter_kernel<<<(N_EDGES * 64) / 256, 256, 0, stream>>>(emb, edge_src,
                                                                 edge_dst, acc);
        float* partials = (float*)(ws + (size_t)N_NODES * D * sizeof(float));
        float* part2    = partials + (size_t)N_TILES * 64;
        final_kernel<<<N_TILES, 256, 0, stream>>>(feat, acc, W1, b1, W2, b2,
                                                  partials);
        reduce1_kernel<<<R1_BLOCKS, 256, 0, stream>>>(partials, part2,
                                                      N_TILES, 25);
        reduce2_kernel<<<1, 256, 0, stream>>>(part2, out);
    }
}

// Round 14
// 169.539 us; speedup vs baseline: 1.0564x; 1.0564x over previous
//
#include <hip/hip_runtime.h>

#define N_NODES 100000
#define N_EDGES 1600000
#define D 64
#define CAP 32         // slot cap per node; Poisson(16): P(deg>32)~1e-5/node
#define OVF_CAP 4096   // global overflow list (backstop)
#define LOVF_CAP 256   // per-block LDS overflow list (R20)
#define N_TILES 1563   // (N_NODES + 63) / 64
#define NR 8           // (legacy fill) region groups
#define SLICE_EDGES 2048
#define N_SLICES 782   // ceil(N_EDGES / SLICE_EDGES)
#define R1_BLOCKS 64   // stage-1 reduce blocks (legacy tiers)
#define ASTRIDE 136    // final LDS row stride in bf16 elems (128 + 8 pad)

// Bucketed partition (R12-proven scan version; R21 scan-free REGRESSED:
// wave-scattered 4B stores to ~64 distinct buckets/wave don't coalesce —
// the scan's bucket-contiguous copy-out is load-bearing) + fused gather.
#define NB2 782        // buckets of 128 nodes (dst>>7)
#define BCAP2 2560     // per-bucket capacity (mean 2048, sigma~45 -> +11 sigma)
#define EPB 4096       // edges per partition block
#define P1_BLOCKS 391  // ceil(N_EDGES / EPB)
#define CVT_BLOCKS 256 // rider blocks: emb->fp8 (+ rid0 zeroes out)

// Persistent-tile final (R18)
#define F2_TPB 3       // tiles per block
#define F2_BLOCKS 521  // 521 * 3 == 1563 exactly

typedef int    vint4  __attribute__((ext_vector_type(4)));
typedef short  s16x4  __attribute__((ext_vector_type(4)));
typedef short  s16x8  __attribute__((ext_vector_type(8)));
typedef float  f32x2  __attribute__((ext_vector_type(2)));
typedef float  f32x4  __attribute__((ext_vector_type(4)));
typedef __bf16 bf16x8 __attribute__((ext_vector_type(8)));  // MFMA operand type

// f32 -> bf16 (RNE). Inputs are finite; NaN path not needed.
__device__ inline short f2bf(float f) {
    unsigned u = __builtin_bit_cast(unsigned, f);
    u += 0x7fffu + ((u >> 16) & 1u);
    return (short)(u >> 16);
}
__device__ inline s16x4 f2bf4(float4 v) {
    s16x4 r; r.x = f2bf(v.x); r.y = f2bf(v.y); r.z = f2bf(v.z); r.w = f2bf(v.w);
    return r;
}
__device__ inline float bf2f(short s) {
    return __builtin_bit_cast(float, ((unsigned)(unsigned short)s) << 16);
}

// ws layout (bytes), top tier:
//   bkt    @ 0        : NB2*BCAP2 int         (8.0 MB)
//   acc16  @ 13201408 : N_NODES*D bf16        (12.8 MB)
//   ovfc   @ 38801408 : int                              } one memset covers
//   bcnt   @ 38801424 : NB2 int (3128 B)                 } ovfc+bcnt
//   ovf    @ 38804560 : OVF_CAP int2          (32 KB)
//   part   @ 38867200 : reduce scratch (legacy tiers)
//   part2  @ 39267328 : R1_BLOCKS*64 float    (16 KB)
//   emb8   @ 39283712 : N_NODES*D bytes       (6.4 MB, OCP e4m3)
#define WS_SLOTS_OFF  401408     // mid-tier CSR slots
#define WS_ACC_OFF    13201408   // mid-tier f32 acc (25.6 MB)
#define WS_ACC16_OFF  13201408
#define WS_OVFC_OFF   38801408
#define WS_BCNT_OFF   38801424
#define WS_OVF_OFF    38804560
#define WS_PART_OFF   38867200
#define WS_PART2_OFF  39267328
#define WS_EMB8_OFF   39283712
#define WS_NEEDED     (WS_PART2_OFF + R1_BLOCKS * 64 * 4)
#define WS_NEEDED16   (WS_EMB8_OFF + N_NODES * D * 2)

// ---------------------------------------------------------------------------
// Pass 1 (R12-proven, R19 grid): edge partition into 782 dst-buckets.
// hist -> ping-pong scan -> LDS-cursor scatter (+bid) -> one global
// atomicAdd per (block,bucket) -> one-thread-per-edge coalesced copy out.
// Rider blocks: emb -> OCP e4m3 via HW cvt_pk_fp8; rid 0 also zeroes out.
// ---------------------------------------------------------------------------
__global__ __launch_bounds__(512) void part_kernel(
    const int* __restrict__ edge_src, const int* __restrict__ edge_dst,
    int* __restrict__ bcnt, int* __restrict__ bkt,
    int* __restrict__ ovf_cnt, int2* __restrict__ ovf,
    const float* __restrict__ emb, unsigned* __restrict__ emb8,
    float* __restrict__ out) {
    const int tid = threadIdx.x;
    if (blockIdx.x >= P1_BLOCKS) {
        const int rid = blockIdx.x - P1_BLOCKS;
        if (rid == 0 && tid < 64) out[tid] = 0.f;
        const float4* e4 = (const float4*)emb;
        const unsigned t0 = rid * 512 + tid;
        for (unsigned j = t0; j < (unsigned)(N_NODES * D / 4);
             j += CVT_BLOCKS * 512) {
            float4 v = e4[j];
            int w = 0;
            w = __builtin_amdgcn_cvt_pk_fp8_f32(v.x, v.y, w, false);
            w = __builtin_amdgcn_cvt_pk_fp8_f32(v.z, v.w, w, true);
            emb8[j] = (unsigned)w;
        }
        return;
    }

    __shared__ int stage[EPB];               // 16 KB
    __shared__ unsigned short bid[EPB];      // 8 KB
    __shared__ int scA[1024];                // 4 KB
    __shared__ int scB[1024];                // 4 KB
    __shared__ int hist[NB2];                // 3.1 KB
    int* const cur   = scB;   // dead after scan
    int* const gbase = scA;   // dead after tot/cur captured

    const int e0 = blockIdx.x * EPB;
    for (int i = tid; i < NB2; i += 512) hist[i] = 0;
    __syncthreads();

    int ss[8], dd[8];
#pragma unroll
    for (int i = 0; i < 8; ++i) {
        const int e = e0 + i * 512 + tid;
        if (e < N_EDGES) { ss[i] = edge_src[e]; dd[i] = edge_dst[e]; }
        else             { ss[i] = 0; dd[i] = -1; }
    }

#pragma unroll
    for (int i = 0; i < 8; ++i)
        if (dd[i] >= 0) atomicAdd(&hist[dd[i] >> 7], 1);
    __syncthreads();

    scA[tid]       = (tid < NB2) ? hist[tid] : 0;
    scA[tid + 512] = 0;
    if (tid + 512 < NB2) scA[tid + 512] = hist[tid + 512];
    __syncthreads();
    {
        int* sA = scA;
        int* sB = scB;
        for (int off = 1; off < 1024; off <<= 1) {
            const int i1 = tid + 512;
            const int v0 = sA[tid] + ((tid >= off) ? sA[tid - off] : 0);
            const int v1 = sA[i1] + sA[i1 - off];
            sB[tid] = v0; sB[i1] = v1;
            __syncthreads();
            int* t = sA; sA = sB; sB = t;
        }
    }
    const int tot = scA[NB2 - 1];
    for (int i = tid; i < NB2; i += 512) cur[i] = scA[i] - hist[i];
    __syncthreads();

#pragma unroll
    for (int i = 0; i < 8; ++i) {
        if (dd[i] >= 0) {
            const int b = dd[i] >> 7;
            const int pos = atomicAdd(&cur[b], 1);
            stage[pos] = (ss[i] << 7) | (dd[i] & 127);
            bid[pos] = (unsigned short)b;
        }
    }
    for (int i = tid; i < NB2; i += 512)
        gbase[i] = atomicAdd(&bcnt[i], hist[i]);
    __syncthreads();

    for (int j = tid; j < tot; j += 512) {
        const int pk = stage[j];
        const int b  = bid[j];
        const int gpos = gbase[b] + (j - (cur[b] - hist[b]));
        if (gpos < BCAP2) {
            bkt[b * BCAP2 + gpos] = pk;
        } else {
            int oj = atomicAdd(ovf_cnt, 1);
            if (oj < OVF_CAP) ovf[oj] = make_int2(pk >> 7, (b << 7) | (pk & 127));
        }
    }
}

// ---------------------------------------------------------------------------
// R20 fused fill+gather+overflow: block = one 128-node bucket, CSR in LDS.
// Phase 1: int atomicAdd directly on __shared__ (ds fast path); node-CAP
// overflow -> per-block LDS side list (global ovf as last backstop).
// Phase 2: register-sum gather, 16 nodes/wave, runtime-deg loop, HW fp8
// decode, bf16 store at the producer. Post-pass (wave 0, serial, same-block
// so no cross-block race): apply LDS side list + any global-ovf entries for
// this bucket via bf16 RMW.
// ---------------------------------------------------------------------------
__global__ __launch_bounds__(512) void fillgather_kernel(
    const int* __restrict__ bcnt, const int* __restrict__ bkt,
    const unsigned* __restrict__ emb8,
    int* __restrict__ ovf_cnt, int2* __restrict__ ovf,
    short* __restrict__ acc16) {
    __shared__ int lcnt[128];
    __shared__ int lslots[128 * CAP];   // 16 KB
    __shared__ int lovf[LOVF_CAP];      // 1 KB: packed (src<<7)|dl
    __shared__ int lovf_cnt;
    const int b = blockIdx.x;
    const int tid = threadIdx.x;
    if (tid < 128) lcnt[tid] = 0;
    if (tid == 0) lovf_cnt = 0;
    __syncthreads();

    int n = bcnt[b];
    if (n > BCAP2) n = BCAP2;
    for (int i = tid; i < n; i += 512) {
        const int pk = bkt[b * BCAP2 + i];
        const int dl = pk & 127;
        const int pos = atomicAdd(&lcnt[dl], 1);    // int LDS atomic (fast)
        if (pos < CAP) {
            lslots[dl * CAP + pos] = pk >> 7;
        } else {
            int j = atomicAdd(&lovf_cnt, 1);
            if (j < LOVF_CAP) {
                lovf[j] = pk;
            } else {
                int g = atomicAdd(ovf_cnt, 1);      // ultimate backstop
                if (g < OVF_CAP) ovf[g] = make_int2(pk >> 7, (b << 7) | dl);
            }
        }
    }
    __syncthreads();

    const int lane = tid & 63;
    const int wave = tid >> 6;
    const int q = lane >> 4;
    const int c = lane & 15;
#pragma unroll 1
    for (int t = 0; t < 16; ++t) {
        const int dl = wave * 16 + t;
        const int v = (b << 7) | dl;
        int deg = lcnt[dl];
        if (deg > CAP) deg = CAP;
        const int si = lslots[dl * CAP + (lane & (CAP - 1))];

        float4 sum = make_float4(0.f, 0.f, 0.f, 0.f);
        for (int e = 0; e < deg; e += 8) {
            const int i0 = e + q, i1 = e + 4 + q;
            const int s0 = __shfl(si, i0 & (CAP - 1));
            const int s1 = __shfl(si, i1 & (CAP - 1));
            unsigned x0 = 0u, x1 = 0u;
            if (i0 < deg) x0 = emb8[(unsigned)s0 * 16 + c];
            if (i1 < deg) x1 = emb8[(unsigned)s1 * 16 + c];
            const f32x2 a0 = __builtin_amdgcn_cvt_pk_f32_fp8((int)x0, false);
            const f32x2 a1 = __builtin_amdgcn_cvt_pk_f32_fp8((int)x0, true);
            const f32x2 b0 = __builtin_amdgcn_cvt_pk_f32_fp8((int)x1, false);
            const f32x2 b1 = __builtin_amdgcn_cvt_pk_f32_fp8((int)x1, true);
            sum.x += a0.x + b0.x;
            sum.y += a0.y + b0.y;
            sum.z += a1.x + b1.x;
            sum.w += a1.y + b1.y;
        }
#pragma unroll
        for (int off = 16; off < 64; off <<= 1) {
            sum.x += __shfl_xor(sum.x, off);
            sum.y += __shfl_xor(sum.y, off);
            sum.z += __shfl_xor(sum.z, off);
            sum.w += __shfl_xor(sum.w, off);
        }
        if (q == 0 && v < N_NODES) {
            *(s16x4*)&acc16[v * D + c * 4] = f2bf4(sum);
        }
    }
    __syncthreads();

    // Post-pass: overflow RMW (typically 0 entries). Wave 0 only; serial
    // over entries (same block -> ordered); 16 lanes x 4 dims per entry.
    if (wave == 0) {
        int nl = lovf_cnt;
        if (nl > LOVF_CAP) nl = LOVF_CAP;
        for (int i = 0; i < nl; ++i) {
            const int pk = lovf[i];
            const int v = (b << 7) | (pk & 127);
            if (lane < 16) {
                const unsigned x = emb8[(unsigned)(pk >> 7) * 16 + lane];
                const f32x2 lo = __builtin_amdgcn_cvt_pk_f32_fp8((int)x, false);
                const f32x2 hi = __builtin_amdgcn_cvt_pk_f32_fp8((int)x, true);
                s16x4 cu = *(s16x4*)&acc16[v * D + lane * 4];
                s16x4 r;
                r.x = f2bf(bf2f(cu.x) + lo.x);
                r.y = f2bf(bf2f(cu.y) + lo.y);
                r.z = f2bf(bf2f(cu.z) + hi.x);
                r.w = f2bf(bf2f(cu.w) + hi.y);
                *(s16x4*)&acc16[v * D + lane * 4] = r;
            }
        }
        int ng = *ovf_cnt;
        if (ng > OVF_CAP) ng = OVF_CAP;
        for (int i = 0; i < ng; ++i) {
            const int2 e = ovf[i];
            if ((e.y >> 7) != b) continue;
            if (lane < 16) {
                const unsigned x = emb8[(unsigned)e.x * 16 + lane];
                const f32x2 lo = __builtin_amdgcn_cvt_pk_f32_fp8((int)x, false);
                const f32x2 hi = __builtin_amdgcn_cvt_pk_f32_fp8((int)x, true);
                s16x4 cu = *(s16x4*)&acc16[e.y * D + lane * 4];
                s16x4 r;
                r.x = f2bf(bf2f(cu.x) + lo.x);
                r.y = f2bf(bf2f(cu.y) + lo.y);
                r.z = f2bf(bf2f(cu.z) + hi.x);
                r.w = f2bf(bf2f(cu.w) + hi.y);
                *(s16x4*)&acc16[e.y * D + lane * 4] = r;
            }
        }
    }
}

// ---------------------------------------------------------------------------
// Legacy region fill + f32 gather + f32 ovf (mid tier / fallback only).
// ---------------------------------------------------------------------------
__global__ __launch_bounds__(256) void fill_kernel(
    const int* __restrict__ edge_src, const int* __restrict__ edge_dst,
    int* __restrict__ cnt, int* __restrict__ slots,
    int* __restrict__ ovf_cnt, int2* __restrict__ ovf) {
    const int r = blockIdx.x & (NR - 1);
    if (r == 7) return;
    const int slice = blockIdx.x >> 3;
    const int base_e = slice * SLICE_EDGES + threadIdx.x * 8;
    if (base_e >= N_EDGES) return;
    const vint4* s4 = (const vint4*)(edge_src + base_e);
    const vint4* d4 = (const vint4*)(edge_dst + base_e);
    vint4 a0 = __builtin_nontemporal_load(s4);
    vint4 a1 = __builtin_nontemporal_load(s4 + 1);
    vint4 b0 = __builtin_nontemporal_load(d4);
    vint4 b1 = __builtin_nontemporal_load(d4 + 1);
    int ss[8] = {a0.x, a0.y, a0.z, a0.w, a1.x, a1.y, a1.z, a1.w};
    int dd[8] = {b0.x, b0.y, b0.z, b0.w, b1.x, b1.y, b1.z, b1.w};
    int pos[8];
#pragma unroll
    for (int i = 0; i < 8; ++i) {
        pos[i] = ((dd[i] >> 14) == r) ? atomicAdd(&cnt[dd[i]], 1) : -1;
    }
#pragma unroll
    for (int i = 0; i < 8; ++i) {
        if (pos[i] >= 0 && pos[i] < CAP) slots[dd[i] * CAP + pos[i]] = ss[i];
    }
#pragma unroll
    for (int i = 0; i < 8; ++i) {
        if (pos[i] >= CAP) {
            int j = atomicAdd(ovf_cnt, 1);
            if (j < OVF_CAP) ovf[j] = make_int2(ss[i], dd[i]);
        }
    }
}

__global__ __launch_bounds__(256) void gather_kernel(
    const float* __restrict__ emb, const int* __restrict__ cnt,
    const int* __restrict__ slots, float* __restrict__ acc) {
    const int lane = threadIdx.x & 63;
    const int wave = threadIdx.x >> 6;
    const int v = blockIdx.x * 4 + wave;
    const int q  = lane >> 4;
    const int c4 = lane & 15;
    int deg = cnt[v];
    if (deg > CAP) deg = CAP;
    const int si = slots[v * CAP + (lane & (CAP - 1))];
    const float4* emb4 = (const float4*)emb;

    float4 sum = make_float4(0.f, 0.f, 0.f, 0.f);
    for (int e = 0; e < deg; e += 4) {
        const int idx = e + q;
        const int s = __shfl(si, idx & (CAP - 1));
        if (idx < deg) {
            float4 a = emb4[s * 16 + c4];
            sum.x += a.x; sum.y += a.y; sum.z += a.z; sum.w += a.w;
        }
    }
#pragma unroll
    for (int off = 16; off < 64; off <<= 1) {
        sum.x += __shfl_xor(sum.x, off);
        sum.y += __shfl_xor(sum.y, off);
        sum.z += __shfl_xor(sum.z, off);
        sum.w += __shfl_xor(sum.w, off);
    }
    if (q == 0) {
        ((float4*)acc)[v * 16 + c4] = sum;
    }
}

__global__ __launch_bounds__(256) void ovf_kernel(
    const float* __restrict__ emb, const int* __restrict__ ovf_cnt,
    const int2* __restrict__ ovf, float* __restrict__ acc) {
    int n = *ovf_cnt;
    if (n > OVF_CAP) n = OVF_CAP;
    const int lane = threadIdx.x & 63;
    const int wv = (blockIdx.x * 256 + threadIdx.x) >> 6;
    const int nwaves = (gridDim.x * 256) >> 6;
    for (int i = wv; i < n; i += nwaves) {
        int2 e = ovf[i];
        unsafeAtomicAdd(&acc[e.y * D + lane], emb[e.x * D + lane]);
    }
}

__global__ __launch_bounds__(256) void scatter_kernel(
    const float* __restrict__ emb,
    const int* __restrict__ edge_src, const int* __restrict__ edge_dst,
    float* __restrict__ acc) {
    int gid = blockIdx.x * 256 + threadIdx.x;
    int e = gid >> 6;
    int c = gid & 63;
    unsafeAtomicAdd(&acc[edge_dst[e] * D + c], emb[edge_src[e] * D + c]);
}

// ---------------------------------------------------------------------------
// R20 persistent-tile final: 521 blocks x 3 tiles; W staged + Bf hoisted once
// per block; per-thread sums across tiles; block result accumulated directly
// into out via unsafeAtomicAdd (out zeroed by part's rider).
// ---------------------------------------------------------------------------
__global__ __launch_bounds__(256) void final_mixed2_kernel(
    const float* __restrict__ feat, const short* __restrict__ acc16,
    const float* __restrict__ W1, const float* __restrict__ b1,
    const float* __restrict__ W2, const float* __restrict__ b2,
    float* __restrict__ out) {
    __shared__ short A_s[64 * ASTRIDE];
    __shared__ short W_s[64 * ASTRIDE];
    __shared__ float red[4][64];

    const int tid  = threadIdx.x;
    const int lane = tid & 63;
    const int wave = tid >> 6;
    const int quad = lane >> 4;
    const int col  = lane & 15;

    float bias[4];
#pragma unroll
    for (int nb = 0; nb < 4; ++nb) {
        const int o = nb * 16 + col;
        bias[nb] = b1[o] + b2[o];
    }

    // Stage W once (f32 -> bf16).
    {
        const float4* W1v = (const float4*)W1;
        const float4* W2v = (const float4*)W2;
#pragma unroll
        for (int i = 0; i < 4; ++i) {
            const int flat = tid + i * 256;   // 0..1023
            const int row = flat >> 4, c4 = flat & 15;
            *(s16x4*)&W_s[row * ASTRIDE + c4 * 4]      = f2bf4(W1v[flat]);
            *(s16x4*)&W_s[row * ASTRIDE + 64 + c4 * 4] = f2bf4(W2v[flat]);
        }
    }
    __syncthreads();

    // Hoist B-fragments once.
    bf16x8 Bf[4][4];
#pragma unroll
    for (int nb = 0; nb < 4; ++nb)
#pragma unroll
        for (int ks = 0; ks < 4; ++ks)
            Bf[nb][ks] = __builtin_bit_cast(bf16x8,
                *(const s16x8*)&W_s[(nb * 16 + col) * ASTRIDE + ks * 32 + quad * 8]);

    float sums[4] = {0.f, 0.f, 0.f, 0.f};

#pragma unroll 1
    for (int t = 0; t < F2_TPB; ++t) {
        const int tile = blockIdx.x * F2_TPB + t;   // 521*3 == 1563: no guard
        const int node0 = tile * 64;

        // Stage A: feat half (f32->bf16) + nbr half (bf16 copy).
        {
            const float4* fv = (const float4*)feat;
#pragma unroll
            for (int i = 0; i < 4; ++i) {
                const int flat = tid + i * 256;
                const int row = flat >> 4, c4 = flat & 15;
                const int node = node0 + row;
                float4 f = make_float4(0.f, 0.f, 0.f, 0.f);
                if (node < N_NODES) f = fv[(size_t)node * 16 + c4];
                *(s16x4*)&A_s[row * ASTRIDE + c4 * 4] = f2bf4(f);
            }
#pragma unroll
            for (int i = 0; i < 2; ++i) {
                const int flat = tid + i * 256;   // 0..511
                const int row = flat >> 3, c = flat & 7;
                const int node = node0 + row;
                s16x8 pk = {0, 0, 0, 0, 0, 0, 0, 0};
                if (node < N_NODES) pk = *(const s16x8*)&acc16[node * D + c * 8];
                *(s16x8*)&A_s[row * ASTRIDE + 64 + c * 8] = pk;
            }
        }
        __syncthreads();

        f32x4 C[4];
#pragma unroll
        for (int nb = 0; nb < 4; ++nb) C[nb] = (f32x4){0.f, 0.f, 0.f, 0.f};
#pragma unroll
        for (int ks = 0; ks < 4; ++ks) {
            const bf16x8 Af = __builtin_bit_cast(bf16x8,
                *(const s16x8*)&A_s[(wave * 16 + col) * ASTRIDE + ks * 32 + quad * 8]);
#pragma unroll
            for (int nb = 0; nb < 4; ++nb)
                C[nb] = __builtin_amdgcn_mfma_f32_16x16x32_bf16(Af, Bf[nb][ks],
                                                                C[nb], 0, 0, 0);
        }

        // Epilogue: bias + ReLU, masked accumulate into per-thread sums.
#pragma unroll
        for (int nb = 0; nb < 4; ++nb) {
#pragma unroll
            for (int reg = 0; reg < 4; ++reg) {
                const int node = node0 + wave * 16 + quad * 4 + reg;
                float u = C[nb][reg] + bias[nb];
                u = (u > 0.f) ? u : 0.f;
                if (node < N_NODES) sums[nb] += u;
            }
        }
        __syncthreads();   // all waves done reading A_s before next overwrite
    }

    // One cross-lane + cross-wave reduction, then atomic into out.
#pragma unroll
    for (int nb = 0; nb < 4; ++nb) {
        sums[nb] += __shfl_xor(sums[nb], 16);
        sums[nb] += __shfl_xor(sums[nb], 32);
        if (lane < 16) red[wave][nb * 16 + lane] = sums[nb];
    }
    __syncthreads();
    if (tid < 64) {
        unsafeAtomicAdd(&out[tid],
            red[0][tid] + red[1][tid] + red[2][tid] + red[3][tid]);
    }
}

// ---------------------------------------------------------------------------
// Legacy f32-input final (mid tier / fallback): one tile per block.
// ---------------------------------------------------------------------------
__global__ __launch_bounds__(256) void final_kernel(
    const float* __restrict__ feat, const float* __restrict__ acc,
    const float* __restrict__ W1, const float* __restrict__ b1,
    const float* __restrict__ W2, const float* __restrict__ b2,
    float* __restrict__ partials) {
    __shared__ short A_s[64 * ASTRIDE];
    __shared__ short W_s[64 * ASTRIDE];
    __shared__ float red[4][64];

    const int tid  = threadIdx.x;
    const int lane = tid & 63;
    const int wave = tid >> 6;
    const int quad = lane >> 4;
    const int col  = lane & 15;
    const int node0 = blockIdx.x * 64;

    float bias[4];
#pragma unroll
    for (int nb = 0; nb < 4; ++nb) {
        const int o = nb * 16 + col;
        bias[nb] = b1[o] + b2[o];
    }

    {
        const float4* W1v = (const float4*)W1;
        const float4* W2v = (const float4*)W2;
#pragma unroll
        for (int i = 0; i < 4; ++i) {
            const int flat = tid + i * 256;
            const int row = flat >> 4, c4 = flat & 15;
            *(s16x4*)&W_s[row * ASTRIDE + c4 * 4]      = f2bf4(W1v[flat]);
            *(s16x4*)&W_s[row * ASTRIDE + 64 + c4 * 4] = f2bf4(W2v[flat]);
        }
    }

    {
        const float4* fv = (const float4*)feat;
        const float4* av = (const float4*)acc;
#pragma unroll
        for (int i = 0; i < 4; ++i) {
            const int flat = tid + i * 256;
            const int row = flat >> 4, c4 = flat & 15;
            const int node = node0 + row;
            float4 f = make_float4(0.f, 0.f, 0.f, 0.f);
            float4 n = make_float4(0.f, 0.f, 0.f, 0.f);
            if (node < N_NODES) {
                f = fv[(size_t)node * 16 + c4];
                n = av[(size_t)node * 16 + c4];
            }
            *(s16x4*)&A_s[row * ASTRIDE + c4 * 4]      = f2bf4(f);
            *(s16x4*)&A_s[row * ASTRIDE + 64 + c4 * 4] = f2bf4(n);
        }
    }
    __syncthreads();

    bf16x8 Bf[4][4];
#pragma unroll
    for (int nb = 0; nb < 4; ++nb)
#pragma unroll
        for (int ks = 0; ks < 4; ++ks)
            Bf[nb][ks] = __builtin_bit_cast(bf16x8,
                *(const s16x8*)&W_s[(nb * 16 + col) * ASTRIDE + ks * 32 + quad * 8]);

    f32x4 C[4];
#pragma unroll
    for (int nb = 0; nb < 4; ++nb) C[nb] = (f32x4){0.f, 0.f, 0.f, 0.f};
#pragma unroll
    for (int ks = 0; ks < 4; ++ks) {
        const bf16x8 Af = __builtin_bit_cast(bf16x8,
            *(const s16x8*)&A_s[(wave * 16 + col) * ASTRIDE + ks * 32 + quad * 8]);
#pragma unroll
        for (int nb = 0; nb < 4; ++nb)
            C[nb] = __builtin_amdgcn_mfma_f32_16x16x32_bf16(Af, Bf[nb][ks],
                                                            C[nb], 0, 0, 0);
    }

    float sums[4] = {0.f, 0.f, 0.f, 0.f};
#pragma unroll
    for (int nb = 0; nb < 4; ++nb) {
#pragma unroll
        for (int reg = 0; reg < 4; ++reg) {
            const int node = node0 + wave * 16 + quad * 4 + reg;
            float u = C[nb][reg] + bias[nb];
            u = (u > 0.f) ? u : 0.f;
            if (node < N_NODES) sums[nb] += u;
        }
        sums[nb] += __shfl_xor(sums[nb], 16);
        sums[nb] += __shfl_xor(sums[nb], 32);
        if (lane < 16) red[wave][nb * 16 + lane] = sums[nb];
    }
    __syncthreads();
    if (tid < 64) {
        partials[blockIdx.x * 64 + tid] =
            red[0][tid] + red[1][tid] + red[2][tid] + red[3][tid];
    }
}

// ---------------------------------------------------------------------------
// Two-stage partials reduction (legacy tiers only).
// ---------------------------------------------------------------------------
__global__ __launch_bounds__(256) void reduce1_kernel(
    const float* __restrict__ partials, float* __restrict__ part2,
    int nrows, int rpb) {
    __shared__ float red[4][64];
    const int col = threadIdx.x & 63;
    const int seg = threadIdx.x >> 6;
    const int r0 = blockIdx.x * rpb;
    int r1 = r0 + rpb;
    if (r1 > nrows) r1 = nrows;
    float s = 0.f;
    for (int r = r0 + seg; r < r1; r += 4) s += partials[r * 64 + col];
    red[seg][col] = s;
    __syncthreads();
    if (seg == 0) {
        part2[blockIdx.x * 64 + col] =
            red[0][col] + red[1][col] + red[2][col] + red[3][col];
    }
}

__global__ __launch_bounds__(256) void reduce2_kernel(
    const float* __restrict__ part2, float* __restrict__ out) {
    __shared__ float red[4][64];
    const int col = threadIdx.x & 63;
    const int seg = threadIdx.x >> 6;
    float s = 0.f;
    for (int r = seg; r < R1_BLOCKS; r += 4) s += part2[r * 64 + col];
    red[seg][col] = s;
    __syncthreads();
    if (seg == 0) {
        out[col] = red[0][col] + red[1][col] + red[2][col] + red[3][col];
    }
}

extern "C" void kernel_launch(void* const* d_in, const int* in_sizes, int n_in,
                              void* d_out, int out_size, void* d_ws, size_t ws_size,
                              hipStream_t stream) {
    const float* feat = (const float*)d_in[0];
    const float* emb  = (const float*)d_in[1];
    const float* W1   = (const float*)d_in[2];
    const float* b1   = (const float*)d_in[3];
    const float* W2   = (const float*)d_in[4];
    const float* b2   = (const float*)d_in[5];
    const int* edge_src = (const int*)d_in[6];
    const int* edge_dst = (const int*)d_in[7];
    float* out = (float*)d_out;
    char* ws = (char*)d_ws;

    if (ws_size >= (size_t)WS_NEEDED16) {
        // R20 path (proven best): 4 dispatches (memset, part, fillgather,
        // final).
        int*      bkt      = (int*)ws;
        short*    acc16    = (short*)(ws + WS_ACC16_OFF);
        int*      ovf_cnt  = (int*)(ws + WS_OVFC_OFF);
        int*      bcnt     = (int*)(ws + WS_BCNT_OFF);
        int2*     ovf      = (int2*)(ws + WS_OVF_OFF);
        unsigned* emb8     = (unsigned*)(ws + WS_EMB8_OFF);

        (void)hipMemsetAsync(ovf_cnt, 0, 16 + NB2 * sizeof(int), stream);

        part_kernel<<<P1_BLOCKS + CVT_BLOCKS, 512, 0, stream>>>(
            edge_src, edge_dst, bcnt, bkt, ovf_cnt, ovf, emb, emb8, out);
        fillgather_kernel<<<NB2, 512, 0, stream>>>(bcnt, bkt, emb8,
                                                   ovf_cnt, ovf, acc16);
        final_mixed2_kernel<<<F2_BLOCKS, 256, 0, stream>>>(feat, acc16, W1, b1,
                                                           W2, b2, out);
    } else if (ws_size >= (size_t)WS_NEEDED) {
        int*   cnt      = (int*)ws;
        int*   slots    = (int*)(ws + WS_SLOTS_OFF);
        float* acc      = (float*)(ws + WS_ACC_OFF);
        int*   ovf_cnt  = (int*)(ws + WS_OVFC_OFF);
        int2*  ovf      = (int2*)(ws + WS_OVF_OFF);
        float* partials = (float*)(ws + WS_PART_OFF);
        float* part2    = (float*)(ws + WS_PART2_OFF);

        (void)hipMemsetAsync(cnt, 0, N_NODES * sizeof(int), stream);
        (void)hipMemsetAsync(ovf_cnt, 0, sizeof(int), stream);

        fill_kernel<<<NR * N_SLICES, 256, 0, stream>>>(edge_src, edge_dst,
                                                       cnt, slots, ovf_cnt, ovf);
        gather_kernel<<<N_NODES / 4, 256, 0, stream>>>(emb, cnt, slots, acc);
        ovf_kernel<<<16, 256, 0, stream>>>(emb, ovf_cnt, ovf, acc);

        final_kernel<<<N_TILES, 256, 0, stream>>>(feat, acc, W1, b1, W2, b2,
                                                  partials);
        reduce1_kernel<<<R1_BLOCKS, 256, 0, stream>>>(partials, part2,
                                                      N_TILES, 25);
        reduce2_kernel<<<1, 256, 0, stream>>>(part2, out);
    } else {
        float* acc = (float*)ws;
        (void)hipMemsetAsync(acc, 0, (size_t)N_NODES * D * sizeof(float), stream);
        scatter_kernel<<<(N_EDGES * 64) / 256, 256, 0, stream>>>(emb, edge_src,
                                                                 edge_dst, acc);
        float* partials = (float*)(ws + (size_t)N_NODES * D * sizeof(float));
        float* part2    = partials + (size_t)N_TILES * 64;
        final_kernel<<<N_TILES, 256, 0, stream>>>(feat, acc, W1, b1, W2, b2,
                                                  partials);
        reduce1_kernel<<<R1_BLOCKS, 256, 0, stream>>>(partials, part2,
                                                      N_TILES, 25);
        reduce2_kernel<<<1, 256, 0, stream>>>(part2, out);
    }
}